// Round 1
// baseline (165.493 us; speedup 1.0000x reference)
//
#include <hip/hip_runtime.h>

#define HH 512
#define WW 512
#define BATCH 32
#define BH 32                // output rows per block (band height)
#define NB (HH / BH)         // 16 bands
#define TPB 128              // 2 waves; 4 cols/thread -> full 512-wide rows
#define VTW 528              // LDS row stride (floats): 8 left halo + 512 + 8 right
#define NBLK (NB * BATCH)    // 512 partial sums

static __device__ __forceinline__ float4 f4zero() {
  return make_float4(0.f, 0.f, 0.f, 0.f);
}

__global__ __launch_bounds__(TPB) void ssim_main(
    const float* __restrict__ img1,
    const float* __restrict__ img2,
    float* __restrict__ partial)
{
  // Gaussian(11, sigma=1.5), normalized — matches np float32 values.
  constexpr float G[11] = {
      0.00102838f, 0.00759876f, 0.03600077f, 0.10936070f, 0.21300553f,
      0.26601171f,
      0.21300553f, 0.10936070f, 0.03600077f, 0.00759876f, 0.00102838f};
  constexpr float C1 = 1.0e-4f;   // 0.01^2
  constexpr float C2 = 9.0e-4f;   // 0.03^2

  const int tid  = threadIdx.x;
  const int band = blockIdx.x;
  const int bat  = blockIdx.y;
  const int r0   = band * BH;
  const float* p1 = img1 + (size_t)bat * (HH * WW);
  const float* p2 = img2 + (size_t)bat * (HH * WW);
  const int c0 = tid * 4;          // this thread's 4 image columns

  // vt[buf][array][col+8]: 5 vertically-blurred rows (mu1,mu2,x2,y2,xy),
  // double-buffered on row parity. Halos are zero => SAME zero padding.
  __shared__ __align__(16) float vt[2][5][VTW];

  if (tid < 8) {
#pragma unroll
    for (int u = 0; u < 2; ++u)
#pragma unroll
      for (int a = 0; a < 5; ++a) {
        vt[u][a][tid]       = 0.f;   // cols -8..-1 (only -5..-1 read)
        vt[u][a][520 + tid] = 0.f;   // cols 512..519
      }
  }

  // Register sliding window: rows r0-5+j for j=0..11 (12 rows), both images.
  float4 w1[12], w2[12];
#pragma unroll
  for (int j = 0; j < 12; ++j) {
    const int r = r0 - 5 + j;
    float4 a = f4zero(), b = f4zero();
    if (r >= 0 && r < HH) {
      a = *(const float4*)(p1 + r * WW + c0);
      b = *(const float4*)(p2 + r * WW + c0);
    }
    w1[j] = a;
    w2[j] = b;
  }

  __syncthreads();   // halo zeros visible before first horizontal pass

  float ssum = 0.f;

#pragma unroll 1
  for (int q = 0; q < BH; q += 2) {
    // Prefetch the two rows needed by the NEXT iteration (consumed at bottom).
    float4 ta1 = f4zero(), ta2 = f4zero(), tb1 = f4zero(), tb2 = f4zero();
    {
      const int ra = r0 + 7 + q;   // always >= 7, only upper guard needed
      const int rb = r0 + 8 + q;
      if (ra < HH) {
        ta1 = *(const float4*)(p1 + ra * WW + c0);
        ta2 = *(const float4*)(p2 + ra * WW + c0);
      }
      if (rb < HH) {
        tb1 = *(const float4*)(p1 + rb * WW + c0);
        tb2 = *(const float4*)(p2 + rb * WW + c0);
      }
    }

#pragma unroll
    for (int s = 0; s < 2; ++s) {
      // ---- vertical blur of the 5 products, output row r0+q+s, in registers
      float acc[5][4];
#pragma unroll
      for (int a = 0; a < 5; ++a)
#pragma unroll
        for (int i = 0; i < 4; ++i) acc[a][i] = 0.f;

#pragma unroll
      for (int k = 0; k < 11; ++k) {
        const float gk = G[k];
        const float4 a4 = w1[k + s];
        const float4 b4 = w2[k + s];
        const float av[4] = {a4.x, a4.y, a4.z, a4.w};
        const float bv[4] = {b4.x, b4.y, b4.z, b4.w};
#pragma unroll
        for (int i = 0; i < 4; ++i) {
          const float t1 = gk * av[i];
          const float t2 = gk * bv[i];
          acc[0][i] += t1;                            // mu1
          acc[1][i] += t2;                            // mu2
          acc[2][i] = fmaf(t1, av[i], acc[2][i]);     // E[x^2]
          acc[3][i] = fmaf(t2, bv[i], acc[3][i]);     // E[y^2]
          acc[4][i] = fmaf(t1, bv[i], acc[4][i]);     // E[xy]
        }
      }

#pragma unroll
      for (int a = 0; a < 5; ++a) {
        ((float4*)(&vt[s][a][8]))[tid] =             // 16B-aligned: 8+4*tid
            make_float4(acc[a][0], acc[a][1], acc[a][2], acc[a][3]);
      }

      __syncthreads();

      // ---- horizontal blur (vectorized LDS reads) + SSIM
      float h[5][4];
#pragma unroll
      for (int a = 0; a < 5; ++a) {
        const float* row = &vt[s][a][0];
        const float4* r4 = (const float4*)row;
        const float4 X0 = r4[tid];
        const float4 X1 = r4[tid + 1];
        const float4 X2 = r4[tid + 2];
        const float4 X3 = r4[tid + 3];
        const float x[17] = {X0.x, X0.y, X0.z, X0.w, X1.x, X1.y, X1.z, X1.w,
                             X2.x, X2.y, X2.z, X2.w, X3.x, X3.y, X3.z, X3.w,
                             row[c0 + 16]};
        // out col c0+j uses image cols c0+j-5+k -> vt idx c0+j+k+3 -> x[j+k+3]
#pragma unroll
        for (int j = 0; j < 4; ++j) {
          float hv = 0.f;
#pragma unroll
          for (int k = 0; k < 11; ++k) hv = fmaf(G[k], x[j + k + 3], hv);
          h[a][j] = hv;
        }
      }

#pragma unroll
      for (int j = 0; j < 4; ++j) {
        const float mu1 = h[0][j], mu2 = h[1][j];
        const float mu12 = mu1 * mu2;
        const float mu1s = mu1 * mu1;
        const float mu2s = mu2 * mu2;
        const float sg1  = h[2][j] - mu1s;
        const float sg2  = h[3][j] - mu2s;
        const float sg12 = h[4][j] - mu12;
        const float num = (2.f * mu12 + C1) * (2.f * sg12 + C2);
        const float den = (mu1s + mu2s + C1) * (sg1 + sg2 + C2);
        ssum += num / den;
      }
    }

    // slide window down two rows
#pragma unroll
    for (int j = 0; j < 10; ++j) { w1[j] = w1[j + 2]; w2[j] = w2[j + 2]; }
    w1[10] = ta1; w2[10] = ta2;
    w1[11] = tb1; w2[11] = tb2;
  }

  // ---- block reduction -> one partial per block (deterministic, no atomics)
#pragma unroll
  for (int off = 32; off > 0; off >>= 1) ssum += __shfl_xor(ssum, off, 64);
  __shared__ float wsum[2];
  if ((tid & 63) == 0) wsum[tid >> 6] = ssum;
  __syncthreads();
  if (tid == 0) partial[bat * NB + band] = wsum[0] + wsum[1];
}

__global__ void ssim_reduce(const float* __restrict__ partial,
                            float* __restrict__ out)
{
  const int t = threadIdx.x;   // 64 threads
  double s = 0.0;
  for (int i = t; i < NBLK; i += 64) s += (double)partial[i];
#pragma unroll
  for (int off = 32; off > 0; off >>= 1) s += __shfl_xor(s, off, 64);
  if (t == 0) out[0] = (float)(s / (double)((size_t)BATCH * HH * WW));
}

extern "C" void kernel_launch(void* const* d_in, const int* in_sizes, int n_in,
                              void* d_out, int out_size, void* d_ws, size_t ws_size,
                              hipStream_t stream) {
  const float* img1 = (const float*)d_in[0];
  const float* img2 = (const float*)d_in[1];
  float* out = (float*)d_out;
  float* partial = (float*)d_ws;   // 512 floats = 2 KB scratch
  dim3 grid(NB, BATCH);
  ssim_main<<<grid, TPB, 0, stream>>>(img1, img2, partial);
  ssim_reduce<<<1, 64, 0, stream>>>(partial, out);
}

// Round 2
// 134.740 us; speedup vs baseline: 1.2282x; 1.2282x over previous
//
#include <hip/hip_runtime.h>

#define HH 512
#define WW 512
#define BATCH 32
#define BH 16                // output rows per block (band height)
#define NB (HH / BH)         // 32 bands
#define TPB 256              // 4 waves; 2 cols/thread -> full 512-wide rows
#define VTW 528              // LDS row stride (floats): 8 left halo + 512 + 8 right
#define NBLOCKS (NB * BATCH) // 1024 blocks

struct WS {
  unsigned counter;   // zeroed by ssim_init
  unsigned pad;
  double accum;       // zeroed by ssim_init
};

__global__ void ssim_init(WS* w) {
  if (threadIdx.x == 0) { w->counter = 0u; w->accum = 0.0; }
}

__global__ __launch_bounds__(TPB, 4) void ssim_main(
    const float* __restrict__ img1,
    const float* __restrict__ img2,
    WS* __restrict__ ws,
    float* __restrict__ out)
{
  // Gaussian(11, sigma=1.5), normalized — matches np float32 values.
  constexpr float G[11] = {
      0.00102838f, 0.00759876f, 0.03600077f, 0.10936070f, 0.21300553f,
      0.26601171f,
      0.21300553f, 0.10936070f, 0.03600077f, 0.00759876f, 0.00102838f};
  constexpr float C1 = 1.0e-4f;   // 0.01^2
  constexpr float C2 = 9.0e-4f;   // 0.03^2

  const int tid  = threadIdx.x;
  const int band = blockIdx.x;
  const int bat  = blockIdx.y;
  const int r0   = band * BH;
  const float* p1 = img1 + (size_t)bat * (HH * WW);
  const float* p2 = img2 + (size_t)bat * (HH * WW);
  const int c0 = tid * 2;          // this thread's 2 image columns

  // vt[buf][array][col+8]: 5 vertically-blurred rows (mu1,mu2,x2,y2,xy),
  // double-buffered on row parity. Halos are zero => SAME zero padding.
  __shared__ __align__(16) float vt[2][5][VTW];

  if (tid < 8) {
#pragma unroll
    for (int u = 0; u < 2; ++u)
#pragma unroll
      for (int a = 0; a < 5; ++a) {
        vt[u][a][tid]       = 0.f;   // left halo cols
        vt[u][a][520 + tid] = 0.f;   // right halo cols
      }
  }

  // Register sliding window: rows r0-5+j for j=0..11 (12 rows), both images.
  float2 w1[12], w2[12];
#pragma unroll
  for (int j = 0; j < 12; ++j) {
    const int r = r0 - 5 + j;
    float2 a = make_float2(0.f, 0.f), b = make_float2(0.f, 0.f);
    if (r >= 0 && r < HH) {
      a = *(const float2*)(p1 + r * WW + c0);
      b = *(const float2*)(p2 + r * WW + c0);
    }
    w1[j] = a;
    w2[j] = b;
  }

  __syncthreads();   // halo zeros visible before first horizontal pass

  float ssum = 0.f;

#pragma unroll 1
  for (int q = 0; q < BH; q += 2) {
    // Prefetch the two rows needed by the NEXT iteration (consumed at bottom).
    float2 ta1 = make_float2(0.f, 0.f), ta2 = ta1, tb1 = ta1, tb2 = ta1;
    const bool pf = (q + 2 < BH);
    if (pf) {
      const int ra = r0 + 7 + q;
      const int rb = r0 + 8 + q;
      if (ra < HH) {
        ta1 = *(const float2*)(p1 + ra * WW + c0);
        ta2 = *(const float2*)(p2 + ra * WW + c0);
      }
      if (rb < HH) {
        tb1 = *(const float2*)(p1 + rb * WW + c0);
        tb2 = *(const float2*)(p2 + rb * WW + c0);
      }
    }

#pragma unroll
    for (int s = 0; s < 2; ++s) {
      // ---- vertical blur of the 5 products, output row r0+q+s, in registers
      float acc[5][2];
#pragma unroll
      for (int a = 0; a < 5; ++a) { acc[a][0] = 0.f; acc[a][1] = 0.f; }

#pragma unroll
      for (int k = 0; k < 11; ++k) {
        const float gk = G[k];
        const float2 a2 = w1[k + s];
        const float2 b2 = w2[k + s];
        const float av[2] = {a2.x, a2.y};
        const float bv[2] = {b2.x, b2.y};
#pragma unroll
        for (int i = 0; i < 2; ++i) {
          const float t1 = gk * av[i];
          const float t2 = gk * bv[i];
          acc[0][i] += t1;                            // mu1
          acc[1][i] += t2;                            // mu2
          acc[2][i] = fmaf(t1, av[i], acc[2][i]);     // E[x^2]
          acc[3][i] = fmaf(t2, bv[i], acc[3][i]);     // E[y^2]
          acc[4][i] = fmaf(t1, bv[i], acc[4][i]);     // E[xy]
        }
      }

#pragma unroll
      for (int a = 0; a < 5; ++a) {
        // float2 store at padded col 8 + c0  ->  float2 index 4 + tid
        ((float2*)(&vt[s][a][0]))[4 + tid] = make_float2(acc[a][0], acc[a][1]);
      }

      __syncthreads();

      // ---- horizontal blur (float2 LDS reads, 2-way bank alias = free) + SSIM
      float h[5][2];
#pragma unroll
      for (int a = 0; a < 5; ++a) {
        const float2* r2 = (const float2*)(&vt[s][a][0]);
        float x[14];   // padded floats c0+2 .. c0+15
#pragma unroll
        for (int m = 0; m < 7; ++m) {
          const float2 v = r2[tid + 1 + m];
          x[2 * m]     = v.x;
          x[2 * m + 1] = v.y;
        }
        // out col c0+j uses padded idx c0+j+k+3 -> x[j+k+1]
#pragma unroll
        for (int j = 0; j < 2; ++j) {
          float hv = 0.f;
#pragma unroll
          for (int k = 0; k < 11; ++k) hv = fmaf(G[k], x[j + k + 1], hv);
          h[a][j] = hv;
        }
      }

#pragma unroll
      for (int j = 0; j < 2; ++j) {
        const float mu1 = h[0][j], mu2 = h[1][j];
        const float mu12 = mu1 * mu2;
        const float mu1s = mu1 * mu1;
        const float mu2s = mu2 * mu2;
        const float sg1  = h[2][j] - mu1s;
        const float sg2  = h[3][j] - mu2s;
        const float sg12 = h[4][j] - mu12;
        const float num = (2.f * mu12 + C1) * (2.f * sg12 + C2);
        const float den = (mu1s + mu2s + C1) * (sg1 + sg2 + C2);
        ssum += num / den;
      }
    }

    // slide window down two rows
#pragma unroll
    for (int j = 0; j < 10; ++j) { w1[j] = w1[j + 2]; w2[j] = w2[j + 2]; }
    w1[10] = ta1; w2[10] = ta2;
    w1[11] = tb1; w2[11] = tb2;
  }

  // ---- block reduction, then device-wide last-block reduction (1 kernel)
#pragma unroll
  for (int off = 32; off > 0; off >>= 1) ssum += __shfl_xor(ssum, off, 64);
  __shared__ float wsum[4];
  if ((tid & 63) == 0) wsum[tid >> 6] = ssum;
  __syncthreads();
  if (tid == 0) {
    const float bsum = wsum[0] + wsum[1] + wsum[2] + wsum[3];
    atomicAdd(&ws->accum, (double)bsum);
    __threadfence();                       // make the add visible device-wide
    const unsigned old = atomicAdd(&ws->counter, 1u);
    if (old == NBLOCKS - 1) {
      // RMW read at the coherence point: returns the completed total.
      const double tot = atomicAdd(&ws->accum, 0.0);
      out[0] = (float)(tot / (double)((size_t)BATCH * HH * WW));
    }
  }
}

extern "C" void kernel_launch(void* const* d_in, const int* in_sizes, int n_in,
                              void* d_out, int out_size, void* d_ws, size_t ws_size,
                              hipStream_t stream) {
  const float* img1 = (const float*)d_in[0];
  const float* img2 = (const float*)d_in[1];
  float* out = (float*)d_out;
  WS* ws = (WS*)d_ws;
  ssim_init<<<1, 64, 0, stream>>>(ws);
  dim3 grid(NB, BATCH);
  ssim_main<<<grid, TPB, 0, stream>>>(img1, img2, ws, out);
}